// Round 1
// baseline (420.988 us; speedup 1.0000x reference)
//
#include <hip/hip_runtime.h>
#include <math.h>

#define N_NODES 50000
#define N_EDGES 800000
#define NFEAT 128
#define NHID 64
#define NCLASS 40
#define LN_EPS 1e-5f

// ---------------- Kernel A: h1 = x @ W1, s_src = h1@a_src, s_dst = h1@a_dst ----
// one wave per node; lane = hidden dim (64)
__global__ __launch_bounds__(256) void k_h1(const float* __restrict__ x,
    const float* __restrict__ W1, const float* __restrict__ a1,
    float* __restrict__ h1, float* __restrict__ s_src, float* __restrict__ s_dst) {
  __shared__ float W1s[NFEAT * NHID];   // 32 KB
  for (int i = threadIdx.x; i < NFEAT * NHID; i += 256) W1s[i] = W1[i];
  __syncthreads();
  int wave = threadIdx.x >> 6, lane = threadIdx.x & 63;
  int r = blockIdx.x * 4 + wave;
  // x row distributed across lanes (2 regs per lane)
  float x0 = x[r * NFEAT + lane];
  float x1 = x[r * NFEAT + 64 + lane];
  float acc = 0.f;
#pragma unroll
  for (int k = 0; k < 64; ++k)
    acc = fmaf(__shfl(x0, k), W1s[k * NHID + lane], acc);
#pragma unroll
  for (int k = 0; k < 64; ++k)
    acc = fmaf(__shfl(x1, k), W1s[(64 + k) * NHID + lane], acc);
  h1[r * NHID + lane] = acc;
  float ps = acc * a1[lane];
  float pd = acc * a1[64 + lane];
#pragma unroll
  for (int off = 32; off; off >>= 1) {
    ps += __shfl_xor(ps, off);
    pd += __shfl_xor(pd, off);
  }
  if (lane == 0) { s_src[r] = ps; s_dst[r] = pd; }
}

// ---------------- Kernel B: edge weights + row histogram -----------------------
__global__ __launch_bounds__(256) void k_edge(const int* __restrict__ ei,
    const float* __restrict__ adj, const float* __restrict__ s_src,
    const float* __restrict__ s_dst, float* __restrict__ w, int* __restrict__ cnt) {
  int e = blockIdx.x * 256 + threadIdx.x;
  if (e >= N_EDGES) return;
  int row = ei[e], col = ei[N_EDGES + e];
  float s = s_src[row] + s_dst[col];
  s = (s > 0.f) ? s : 0.2f * s;                 // leaky_relu(0.2)
  float wv = adj[e] / (1.f + __expf(-s));       // sigmoid * adj
  w[e] = wv;
  atomicAdd(&cnt[row], 1);
}

// ---------------- Scan (3 kernels): exclusive prefix over cnt -> row_ptr -------
__global__ __launch_bounds__(256) void k_scan1(const int* __restrict__ cnt,
    int* __restrict__ excl, int* __restrict__ bsum) {
  __shared__ int sd[256];
  int t = threadIdx.x;
  int i = blockIdx.x * 256 + t;
  int v = (i < N_NODES) ? cnt[i] : 0;
  sd[t] = v;
  __syncthreads();
#pragma unroll
  for (int off = 1; off < 256; off <<= 1) {
    int a = (t >= off) ? sd[t - off] : 0;
    __syncthreads();
    sd[t] += a;
    __syncthreads();
  }
  if (i < N_NODES) excl[i] = sd[t] - v;
  if (t == 255) bsum[blockIdx.x] = sd[255];
}

__global__ __launch_bounds__(256) void k_scan2(const int* __restrict__ bsum,
    int* __restrict__ boff, int nb, int* __restrict__ row_ptr_end) {
  __shared__ int sd[256];
  int t = threadIdx.x;
  int v = (t < nb) ? bsum[t] : 0;
  sd[t] = v;
  __syncthreads();
#pragma unroll
  for (int off = 1; off < 256; off <<= 1) {
    int a = (t >= off) ? sd[t - off] : 0;
    __syncthreads();
    sd[t] += a;
    __syncthreads();
  }
  boff[t] = sd[t] - v;
  if (t == 255) *row_ptr_end = sd[255];
}

__global__ __launch_bounds__(256) void k_scan3(int* __restrict__ row_ptr,
    const int* __restrict__ boff) {
  int i = blockIdx.x * 256 + threadIdx.x;
  if (i < N_NODES) row_ptr[i] += boff[blockIdx.x];
}

// ---------------- Kernel D: scatter edges into CSR order -----------------------
__global__ __launch_bounds__(256) void k_scatter(const int* __restrict__ ei,
    const float* __restrict__ w, const int* __restrict__ row_ptr,
    int* __restrict__ fill, int2* __restrict__ edata) {
  int e = blockIdx.x * 256 + threadIdx.x;
  if (e >= N_EDGES) return;
  int row = ei[e], col = ei[N_EDGES + e];
  int p = row_ptr[row] + atomicAdd(&fill[row], 1);
  edata[p] = make_int2(col, __float_as_int(w[e]));
}

// ---------------- Kernel E: agg1 (gather) + ReLU + h2 = h1_out @ W2 ------------
__global__ __launch_bounds__(256) void k_agg1(const float* __restrict__ h1,
    const int2* __restrict__ edata, const int* __restrict__ row_ptr,
    const float* __restrict__ W2, float* __restrict__ h2) {
  __shared__ float W2s[NHID * NCLASS];  // 10 KB
  __shared__ float accs[4][NHID];
  for (int i = threadIdx.x; i < NHID * NCLASS; i += 256) W2s[i] = W2[i];
  int wave = threadIdx.x >> 6, lane = threadIdx.x & 63;
  int r = blockIdx.x * 4 + wave;
  int start = row_ptr[r], end = row_ptr[r + 1];
  float acc = 0.f;
  for (int p = start; p < end; ++p) {
    int2 ed = edata[p];
    acc = fmaf(__int_as_float(ed.y), h1[ed.x * NHID + lane], acc);
  }
  accs[wave][lane] = fmaxf(acc, 0.f);   // ReLU(h1_out)
  __syncthreads();
  if (lane < NCLASS) {
    float s = 0.f;
#pragma unroll
    for (int j = 0; j < NHID; ++j)
      s = fmaf(accs[wave][j], W2s[j * NCLASS + lane], s);
    h2[r * NCLASS + lane] = s;
  }
}

// ---------------- Kernel F: agg2 + ReLU + residual GEMM + LayerNorm ------------
__global__ __launch_bounds__(256) void k_agg2(const float* __restrict__ x,
    const float* __restrict__ h2, const int2* __restrict__ edata,
    const int* __restrict__ row_ptr, const float* __restrict__ res_w,
    const float* __restrict__ res_b, const float* __restrict__ ln_g,
    const float* __restrict__ ln_b, float* __restrict__ out) {
  __shared__ float rwT[NFEAT][NCLASS + 1];  // transposed res_w, +1 pad: ~21 KB
  __shared__ float xs[4][NFEAT];
  for (int i = threadIdx.x; i < NCLASS * NFEAT; i += 256) {
    int j = i / NFEAT, k = i % NFEAT;       // res_w is [NCLASS][NFEAT]
    rwT[k][j] = res_w[i];
  }
  int wave = threadIdx.x >> 6, lane = threadIdx.x & 63;
  int r = blockIdx.x * 4 + wave;
  xs[wave][lane] = x[r * NFEAT + lane];
  xs[wave][64 + lane] = x[r * NFEAT + 64 + lane];
  __syncthreads();
  int start = row_ptr[r], end = row_ptr[r + 1];
  float y = 0.f;
  if (lane < NCLASS) {
    float acc = 0.f;
    for (int p = start; p < end; ++p) {
      int2 ed = edata[p];
      acc = fmaf(__int_as_float(ed.y), h2[ed.x * NCLASS + lane], acc);
    }
    float resv = res_b[lane];
#pragma unroll
    for (int k = 0; k < NFEAT; ++k)
      resv = fmaf(xs[wave][k], rwT[k][lane], resv);
    y = fmaxf(acc, 0.f) + resv;
  }
  // LayerNorm over 40 classes (lanes >= 40 contribute 0)
  float s1 = y, s2 = y * y;
#pragma unroll
  for (int off = 32; off; off >>= 1) {
    s1 += __shfl_xor(s1, off);
    s2 += __shfl_xor(s2, off);
  }
  float mu = s1 / (float)NCLASS;
  float var = s2 / (float)NCLASS - mu * mu;
  float inv = rsqrtf(var + LN_EPS);
  if (lane < NCLASS)
    out[r * NCLASS + lane] = (y - mu) * inv * ln_g[lane] + ln_b[lane];
}

// -------------------------------------------------------------------------------
extern "C" void kernel_launch(void* const* d_in, const int* in_sizes, int n_in,
                              void* d_out, int out_size, void* d_ws, size_t ws_size,
                              hipStream_t stream) {
  const float* x     = (const float*)d_in[0];
  const int*   ei    = (const int*)  d_in[1];
  const float* adj   = (const float*)d_in[2];
  const float* W1    = (const float*)d_in[3];
  const float* a1    = (const float*)d_in[4];
  const float* W2    = (const float*)d_in[5];
  const float* res_w = (const float*)d_in[6];
  const float* res_b = (const float*)d_in[7];
  const float* ln_g  = (const float*)d_in[8];
  const float* ln_b  = (const float*)d_in[9];
  float* out = (float*)d_out;

  char* ws = (char*)d_ws;
  size_t off = 0;
  auto alloc = [&](size_t bytes) -> void* {
    void* p = (void*)(ws + off);
    off += (bytes + 255) & ~(size_t)255;
    return p;
  };

  float* h1       = (float*)alloc((size_t)N_NODES * NHID * 4);
  float* s_src    = (float*)alloc((size_t)N_NODES * 4);
  float* s_dst    = (float*)alloc((size_t)N_NODES * 4);
  float* w        = (float*)alloc((size_t)N_EDGES * 4);
  int*   cnt      = (int*)  alloc((size_t)N_NODES * 4);
  int*   row_ptr  = (int*)  alloc((size_t)(N_NODES + 1) * 4);
  int*   bsum     = (int*)  alloc(256 * 4);
  int*   boff     = (int*)  alloc(256 * 4);
  int2*  edata    = (int2*) alloc((size_t)N_EDGES * 8);
  float* h2       = (float*)alloc((size_t)N_NODES * NCLASS * 4);
  (void)ws_size; (void)in_sizes; (void)n_in; (void)out_size;

  const int NBLK_NODE = N_NODES / 4;            // 12500 (exact)
  const int NBLK_EDGE = (N_EDGES + 255) / 256;  // 3125 (exact)
  const int NBLK_SCAN = (N_NODES + 255) / 256;  // 196

  hipMemsetAsync(cnt, 0, (size_t)N_NODES * 4, stream);
  k_h1<<<NBLK_NODE, 256, 0, stream>>>(x, W1, a1, h1, s_src, s_dst);
  k_edge<<<NBLK_EDGE, 256, 0, stream>>>(ei, adj, s_src, s_dst, w, cnt);
  k_scan1<<<NBLK_SCAN, 256, 0, stream>>>(cnt, row_ptr, bsum);
  k_scan2<<<1, 256, 0, stream>>>(bsum, boff, NBLK_SCAN, row_ptr + N_NODES);
  k_scan3<<<NBLK_SCAN, 256, 0, stream>>>(row_ptr, boff);
  hipMemsetAsync(cnt, 0, (size_t)N_NODES * 4, stream);
  k_scatter<<<NBLK_EDGE, 256, 0, stream>>>(ei, w, row_ptr, cnt, edata);
  k_agg1<<<NBLK_NODE, 256, 0, stream>>>(h1, edata, row_ptr, W2, h2);
  k_agg2<<<NBLK_NODE, 256, 0, stream>>>(x, h2, edata, row_ptr, res_w, res_b,
                                        ln_g, ln_b, out);
}

// Round 2
// 352.557 us; speedup vs baseline: 1.1941x; 1.1941x over previous
//
#include <hip/hip_runtime.h>
#include <math.h>

#define N_NODES 50000
#define N_EDGES 800000
#define NFEAT 128
#define NHID 64
#define NCLASS 40
#define LN_EPS 1e-5f

// ---------------- Kernel A: h1 = x @ W1, s_src = h1@a_src, s_dst = h1@a_dst ----
// one wave per node; lane = hidden dim (64)
__global__ __launch_bounds__(256) void k_h1(const float* __restrict__ x,
    const float* __restrict__ W1, const float* __restrict__ a1,
    float* __restrict__ h1, float* __restrict__ s_src, float* __restrict__ s_dst) {
  __shared__ float W1s[NFEAT * NHID];   // 32 KB
  for (int i = threadIdx.x; i < NFEAT * NHID; i += 256) W1s[i] = W1[i];
  __syncthreads();
  int wave = threadIdx.x >> 6, lane = threadIdx.x & 63;
  int r = blockIdx.x * 4 + wave;
  float x0 = x[r * NFEAT + lane];
  float x1 = x[r * NFEAT + 64 + lane];
  float acc = 0.f;
#pragma unroll
  for (int k = 0; k < 64; ++k)
    acc = fmaf(__shfl(x0, k), W1s[k * NHID + lane], acc);
#pragma unroll
  for (int k = 0; k < 64; ++k)
    acc = fmaf(__shfl(x1, k), W1s[(64 + k) * NHID + lane], acc);
  h1[r * NHID + lane] = acc;
  float ps = acc * a1[lane];
  float pd = acc * a1[64 + lane];
#pragma unroll
  for (int off = 32; off; off >>= 1) {
    ps += __shfl_xor(ps, off);
    pd += __shfl_xor(pd, off);
  }
  if (lane == 0) { s_src[r] = ps; s_dst[r] = pd; }
}

// ---------------- Kernel R: res = x @ res_w^T + res_b --------------------------
__global__ __launch_bounds__(256) void k_res(const float* __restrict__ x,
    const float* __restrict__ res_w, const float* __restrict__ res_b,
    float* __restrict__ res) {
  __shared__ float rwT[NFEAT][NCLASS + 1];  // transposed res_w, +1 pad: ~21 KB
  __shared__ float xs[4][NFEAT];
  for (int i = threadIdx.x; i < NCLASS * NFEAT; i += 256) {
    int j = i / NFEAT, k = i % NFEAT;       // res_w is [NCLASS][NFEAT]
    rwT[k][j] = res_w[i];
  }
  int wave = threadIdx.x >> 6, lane = threadIdx.x & 63;
  int r = blockIdx.x * 4 + wave;
  xs[wave][lane] = x[r * NFEAT + lane];
  xs[wave][64 + lane] = x[r * NFEAT + 64 + lane];
  __syncthreads();
  if (lane < NCLASS) {
    float resv = res_b[lane];
#pragma unroll
    for (int k = 0; k < NFEAT; ++k)
      resv = fmaf(xs[wave][k], rwT[k][lane], resv);
    res[r * NCLASS + lane] = resv;
  }
}

// ---------------- Kernel B: edge weights + row histogram -----------------------
__global__ __launch_bounds__(256) void k_edge(const int* __restrict__ ei,
    const float* __restrict__ adj, const float* __restrict__ s_src,
    const float* __restrict__ s_dst, float* __restrict__ w, int* __restrict__ cnt) {
  int e = blockIdx.x * 256 + threadIdx.x;
  if (e >= N_EDGES) return;
  int row = ei[e], col = ei[N_EDGES + e];
  float s = s_src[row] + s_dst[col];
  s = (s > 0.f) ? s : 0.2f * s;                 // leaky_relu(0.2)
  float wv = adj[e] / (1.f + __expf(-s));       // sigmoid * adj
  w[e] = wv;
  atomicAdd(&cnt[row], 1);
}

// ---------------- Scan (3 kernels): exclusive prefix over cnt -> row_ptr -------
__global__ __launch_bounds__(256) void k_scan1(const int* __restrict__ cnt,
    int* __restrict__ excl, int* __restrict__ bsum) {
  __shared__ int sd[256];
  int t = threadIdx.x;
  int i = blockIdx.x * 256 + t;
  int v = (i < N_NODES) ? cnt[i] : 0;
  sd[t] = v;
  __syncthreads();
#pragma unroll
  for (int off = 1; off < 256; off <<= 1) {
    int a = (t >= off) ? sd[t - off] : 0;
    __syncthreads();
    sd[t] += a;
    __syncthreads();
  }
  if (i < N_NODES) excl[i] = sd[t] - v;
  if (t == 255) bsum[blockIdx.x] = sd[255];
}

__global__ __launch_bounds__(256) void k_scan2(const int* __restrict__ bsum,
    int* __restrict__ boff, int nb, int* __restrict__ row_ptr_end) {
  __shared__ int sd[256];
  int t = threadIdx.x;
  int v = (t < nb) ? bsum[t] : 0;
  sd[t] = v;
  __syncthreads();
#pragma unroll
  for (int off = 1; off < 256; off <<= 1) {
    int a = (t >= off) ? sd[t - off] : 0;
    __syncthreads();
    sd[t] += a;
    __syncthreads();
  }
  boff[t] = sd[t] - v;
  if (t == 255) *row_ptr_end = sd[255];
}

__global__ __launch_bounds__(256) void k_scan3(int* __restrict__ row_ptr,
    const int* __restrict__ boff) {
  int i = blockIdx.x * 256 + threadIdx.x;
  if (i < N_NODES) row_ptr[i] += boff[blockIdx.x];
}

// ---------------- Kernel D: scatter edges into CSR order -----------------------
__global__ __launch_bounds__(256) void k_scatter(const int* __restrict__ ei,
    const float* __restrict__ w, const int* __restrict__ row_ptr,
    int* __restrict__ fill, int2* __restrict__ edata) {
  int e = blockIdx.x * 256 + threadIdx.x;
  if (e >= N_EDGES) return;
  int row = ei[e], col = ei[N_EDGES + e];
  int p = row_ptr[row] + atomicAdd(&fill[row], 1);
  edata[p] = make_int2(col, __float_as_int(w[e]));
}

// ---------------- Kernel E: agg1 (gather, unroll 4) + ReLU + h2 = h1_out @ W2 --
__global__ __launch_bounds__(256) void k_agg1(const float* __restrict__ h1,
    const int2* __restrict__ edata, const int* __restrict__ row_ptr,
    const float* __restrict__ W2, float* __restrict__ h2) {
  __shared__ float W2s[NHID * NCLASS];  // 10 KB
  __shared__ float accs[4][NHID];
  for (int i = threadIdx.x; i < NHID * NCLASS; i += 256) W2s[i] = W2[i];
  int wave = threadIdx.x >> 6, lane = threadIdx.x & 63;
  int r = blockIdx.x * 4 + wave;
  int start = row_ptr[r], end = row_ptr[r + 1];
  float acc = 0.f;
  int p = start;
  for (; p + 3 < end; p += 4) {
    int2 e0 = edata[p], e1 = edata[p + 1], e2 = edata[p + 2], e3 = edata[p + 3];
    float v0 = h1[e0.x * NHID + lane];
    float v1 = h1[e1.x * NHID + lane];
    float v2 = h1[e2.x * NHID + lane];
    float v3 = h1[e3.x * NHID + lane];
    acc = fmaf(__int_as_float(e0.y), v0, acc);
    acc = fmaf(__int_as_float(e1.y), v1, acc);
    acc = fmaf(__int_as_float(e2.y), v2, acc);
    acc = fmaf(__int_as_float(e3.y), v3, acc);
  }
  for (; p < end; ++p) {
    int2 ed = edata[p];
    acc = fmaf(__int_as_float(ed.y), h1[ed.x * NHID + lane], acc);
  }
  accs[wave][lane] = fmaxf(acc, 0.f);   // ReLU(h1_out)
  __syncthreads();
  if (lane < NCLASS) {
    float s = 0.f;
#pragma unroll
    for (int j = 0; j < NHID; ++j)
      s = fmaf(accs[wave][j], W2s[j * NCLASS + lane], s);
    h2[r * NCLASS + lane] = s;
  }
}

// ---------------- Kernel F: agg2 (gather, unroll 4) + ReLU + res + LayerNorm ---
__global__ __launch_bounds__(256) void k_agg2(const float* __restrict__ h2,
    const int2* __restrict__ edata, const int* __restrict__ row_ptr,
    const float* __restrict__ res, const float* __restrict__ ln_g,
    const float* __restrict__ ln_b, float* __restrict__ out) {
  int wave = threadIdx.x >> 6, lane = threadIdx.x & 63;
  int r = blockIdx.x * 4 + wave;
  int start = row_ptr[r], end = row_ptr[r + 1];
  float y = 0.f;
  if (lane < NCLASS) {
    float acc = 0.f;
    int p = start;
    for (; p + 3 < end; p += 4) {
      int2 e0 = edata[p], e1 = edata[p + 1], e2 = edata[p + 2], e3 = edata[p + 3];
      float v0 = h2[e0.x * NCLASS + lane];
      float v1 = h2[e1.x * NCLASS + lane];
      float v2 = h2[e2.x * NCLASS + lane];
      float v3 = h2[e3.x * NCLASS + lane];
      acc = fmaf(__int_as_float(e0.y), v0, acc);
      acc = fmaf(__int_as_float(e1.y), v1, acc);
      acc = fmaf(__int_as_float(e2.y), v2, acc);
      acc = fmaf(__int_as_float(e3.y), v3, acc);
    }
    for (; p < end; ++p) {
      int2 ed = edata[p];
      acc = fmaf(__int_as_float(ed.y), h2[ed.x * NCLASS + lane], acc);
    }
    y = fmaxf(acc, 0.f) + res[r * NCLASS + lane];
  }
  // LayerNorm over 40 classes (lanes >= 40 contribute 0)
  float s1 = y, s2 = y * y;
#pragma unroll
  for (int off = 32; off; off >>= 1) {
    s1 += __shfl_xor(s1, off);
    s2 += __shfl_xor(s2, off);
  }
  float mu = s1 / (float)NCLASS;
  float var = s2 / (float)NCLASS - mu * mu;
  float inv = rsqrtf(var + LN_EPS);
  if (lane < NCLASS)
    out[r * NCLASS + lane] = (y - mu) * inv * ln_g[lane] + ln_b[lane];
}

// -------------------------------------------------------------------------------
extern "C" void kernel_launch(void* const* d_in, const int* in_sizes, int n_in,
                              void* d_out, int out_size, void* d_ws, size_t ws_size,
                              hipStream_t stream) {
  const float* x     = (const float*)d_in[0];
  const int*   ei    = (const int*)  d_in[1];
  const float* adj   = (const float*)d_in[2];
  const float* W1    = (const float*)d_in[3];
  const float* a1    = (const float*)d_in[4];
  const float* W2    = (const float*)d_in[5];
  const float* res_w = (const float*)d_in[6];
  const float* res_b = (const float*)d_in[7];
  const float* ln_g  = (const float*)d_in[8];
  const float* ln_b  = (const float*)d_in[9];
  float* out = (float*)d_out;

  char* ws = (char*)d_ws;
  size_t off = 0;
  auto alloc = [&](size_t bytes) -> void* {
    void* p = (void*)(ws + off);
    off += (bytes + 255) & ~(size_t)255;
    return p;
  };

  float* h1       = (float*)alloc((size_t)N_NODES * NHID * 4);
  float* s_src    = (float*)alloc((size_t)N_NODES * 4);
  float* s_dst    = (float*)alloc((size_t)N_NODES * 4);
  float* w        = (float*)alloc((size_t)N_EDGES * 4);
  int*   cnt      = (int*)  alloc((size_t)N_NODES * 4);
  int*   row_ptr  = (int*)  alloc((size_t)(N_NODES + 1) * 4);
  int*   bsum     = (int*)  alloc(256 * 4);
  int*   boff     = (int*)  alloc(256 * 4);
  int2*  edata    = (int2*) alloc((size_t)N_EDGES * 8);
  float* h2       = (float*)alloc((size_t)N_NODES * NCLASS * 4);
  float* res      = (float*)alloc((size_t)N_NODES * NCLASS * 4);
  (void)ws_size; (void)in_sizes; (void)n_in; (void)out_size;

  const int NBLK_NODE = N_NODES / 4;            // 12500 (exact)
  const int NBLK_EDGE = (N_EDGES + 255) / 256;  // 3125 (exact)
  const int NBLK_SCAN = (N_NODES + 255) / 256;  // 196

  hipMemsetAsync(cnt, 0, (size_t)N_NODES * 4, stream);
  k_h1<<<NBLK_NODE, 256, 0, stream>>>(x, W1, a1, h1, s_src, s_dst);
  k_res<<<NBLK_NODE, 256, 0, stream>>>(x, res_w, res_b, res);
  k_edge<<<NBLK_EDGE, 256, 0, stream>>>(ei, adj, s_src, s_dst, w, cnt);
  k_scan1<<<NBLK_SCAN, 256, 0, stream>>>(cnt, row_ptr, bsum);
  k_scan2<<<1, 256, 0, stream>>>(bsum, boff, NBLK_SCAN, row_ptr + N_NODES);
  k_scan3<<<NBLK_SCAN, 256, 0, stream>>>(row_ptr, boff);
  hipMemsetAsync(cnt, 0, (size_t)N_NODES * 4, stream);
  k_scatter<<<NBLK_EDGE, 256, 0, stream>>>(ei, w, row_ptr, cnt, edata);
  k_agg1<<<NBLK_NODE, 256, 0, stream>>>(h1, edata, row_ptr, W2, h2);
  k_agg2<<<NBLK_NODE, 256, 0, stream>>>(h2, edata, row_ptr, res, ln_g, ln_b, out);
}

// Round 3
// 252.924 us; speedup vs baseline: 1.6645x; 1.3939x over previous
//
#include <hip/hip_runtime.h>
#include <math.h>

#define N_NODES 50000
#define N_EDGES 800000
#define NFEAT 128
#define NHID 64
#define NCLASS 40
#define LN_EPS 1e-5f

__device__ __forceinline__ int swz(int k) { return ((k >> 2) & 7) << 2; }

// ------ Kernel A: h1 = x @ W1 (reg-blocked 4x4) + fused s_src/s_dst ------------
// block: 64 rows x 64 cols, 256 threads, thread = 4 rows x 4 cols
__global__ __launch_bounds__(256) void k_h1mm(const float* __restrict__ x,
    const float* __restrict__ W1, const float* __restrict__ a1,
    float* __restrict__ h1, float* __restrict__ s_src, float* __restrict__ s_dst) {
  __shared__ float xT[NFEAT * 64];    // [k][r ^ swz(k)]  32 KB
  __shared__ float W1s[NFEAT * NHID]; // [k][c]           32 KB
  int t = threadIdx.x;
  int R0 = blockIdx.x * 64;
  for (int i = t; i < NFEAT * NHID / 4; i += 256)
    ((float4*)W1s)[i] = ((const float4*)W1)[i];
#pragma unroll
  for (int it = 0; it < 8; ++it) {
    int i = t + it * 256;
    int r = i >> 5, kq = i & 31;
    int gr = R0 + r;
    float4 v = make_float4(0.f, 0.f, 0.f, 0.f);
    if (gr < N_NODES) v = *(const float4*)(x + (size_t)gr * NFEAT + kq * 4);
    int rw = r ^ ((kq & 7) << 2);
    xT[(kq * 4 + 0) * 64 + rw] = v.x;
    xT[(kq * 4 + 1) * 64 + rw] = v.y;
    xT[(kq * 4 + 2) * 64 + rw] = v.z;
    xT[(kq * 4 + 3) * 64 + rw] = v.w;
  }
  __syncthreads();
  int cg = t & 15, rg = t >> 4;
  int c0 = cg * 4, r0 = rg * 4;
  float acc[4][4] = {};
#pragma unroll 4
  for (int k = 0; k < NFEAT; ++k) {
    float4 xv = *(const float4*)&xT[k * 64 + (r0 ^ swz(k))];
    float4 wv = *(const float4*)&W1s[k * NHID + c0];
    float xr[4] = {xv.x, xv.y, xv.z, xv.w};
    float wr[4] = {wv.x, wv.y, wv.z, wv.w};
#pragma unroll
    for (int j = 0; j < 4; ++j)
#pragma unroll
      for (int c = 0; c < 4; ++c)
        acc[j][c] = fmaf(xr[j], wr[c], acc[j][c]);
  }
  float4 as = *(const float4*)(a1 + c0);
  float4 ad = *(const float4*)(a1 + NHID + c0);
  float asr[4] = {as.x, as.y, as.z, as.w};
  float adr[4] = {ad.x, ad.y, ad.z, ad.w};
  float ps[4], pd[4];
#pragma unroll
  for (int j = 0; j < 4; ++j) {
    int gr = R0 + r0 + j;
    if (gr < N_NODES) {
      float4 o = make_float4(acc[j][0], acc[j][1], acc[j][2], acc[j][3]);
      *(float4*)(h1 + (size_t)gr * NHID + c0) = o;
    }
    float s = 0.f, d = 0.f;
#pragma unroll
    for (int c = 0; c < 4; ++c) {
      s = fmaf(acc[j][c], asr[c], s);
      d = fmaf(acc[j][c], adr[c], d);
    }
    ps[j] = s; pd[j] = d;
  }
#pragma unroll
  for (int j = 0; j < 4; ++j)
#pragma unroll
    for (int off = 1; off < 16; off <<= 1) {
      ps[j] += __shfl_xor(ps[j], off);
      pd[j] += __shfl_xor(pd[j], off);
    }
  if (cg == 0) {
#pragma unroll
    for (int j = 0; j < 4; ++j) {
      int gr = R0 + r0 + j;
      if (gr < N_NODES) { s_src[gr] = ps[j]; s_dst[gr] = pd[j]; }
    }
  }
}

// ------ Kernel R: res = x @ res_w^T + res_b (reg-blocked 4x5) ------------------
// block: 128 rows x 40 cols, 256 threads, thread = 4 rows x 5 cols
__global__ __launch_bounds__(256) void k_resmm(const float* __restrict__ x,
    const float* __restrict__ res_w, const float* __restrict__ res_b,
    float* __restrict__ res) {
  __shared__ float xT[NFEAT * 128];    // [k][r ^ swz(k)]  64 KB
  __shared__ float rwT[NFEAT * NCLASS]; // [k][c]          20 KB
  int t = threadIdx.x;
  int R0 = blockIdx.x * 128;
  for (int i = t; i < NCLASS * NFEAT; i += 256) {
    int c = i / NFEAT, k = i % NFEAT;  // res_w is [NCLASS][NFEAT]
    rwT[k * NCLASS + c] = res_w[i];
  }
#pragma unroll
  for (int it = 0; it < 16; ++it) {
    int i = t + it * 256;
    int r = i >> 5, kq = i & 31;
    int gr = R0 + r;
    float4 v = make_float4(0.f, 0.f, 0.f, 0.f);
    if (gr < N_NODES) v = *(const float4*)(x + (size_t)gr * NFEAT + kq * 4);
    int rw = r ^ ((kq & 7) << 2);
    xT[(kq * 4 + 0) * 128 + rw] = v.x;
    xT[(kq * 4 + 1) * 128 + rw] = v.y;
    xT[(kq * 4 + 2) * 128 + rw] = v.z;
    xT[(kq * 4 + 3) * 128 + rw] = v.w;
  }
  __syncthreads();
  int cg = t & 7, rg = t >> 3;
  int c0 = cg * 5, r0 = rg * 4;
  float acc[4][5] = {};
#pragma unroll 4
  for (int k = 0; k < NFEAT; ++k) {
    float4 xv = *(const float4*)&xT[k * 128 + (r0 ^ swz(k))];
    float xr[4] = {xv.x, xv.y, xv.z, xv.w};
    float wr[5];
#pragma unroll
    for (int c = 0; c < 5; ++c) wr[c] = rwT[k * NCLASS + c0 + c];
#pragma unroll
    for (int j = 0; j < 4; ++j)
#pragma unroll
      for (int c = 0; c < 5; ++c)
        acc[j][c] = fmaf(xr[j], wr[c], acc[j][c]);
  }
  float bb[5];
#pragma unroll
  for (int c = 0; c < 5; ++c) bb[c] = res_b[c0 + c];
#pragma unroll
  for (int j = 0; j < 4; ++j) {
    int gr = R0 + r0 + j;
    if (gr < N_NODES) {
#pragma unroll
      for (int c = 0; c < 5; ++c)
        res[(size_t)gr * NCLASS + c0 + c] = acc[j][c] + bb[c];
    }
  }
}

// ---------------- Kernel B: edge weights + row histogram -----------------------
__global__ __launch_bounds__(256) void k_edge(const int* __restrict__ ei,
    const float* __restrict__ adj, const float* __restrict__ s_src,
    const float* __restrict__ s_dst, float* __restrict__ w, int* __restrict__ cnt) {
  int e = blockIdx.x * 256 + threadIdx.x;
  if (e >= N_EDGES) return;
  int row = ei[e], col = ei[N_EDGES + e];
  float s = s_src[row] + s_dst[col];
  s = (s > 0.f) ? s : 0.2f * s;                 // leaky_relu(0.2)
  float wv = adj[e] / (1.f + __expf(-s));       // sigmoid * adj
  w[e] = wv;
  atomicAdd(&cnt[row], 1);
}

// ---------------- Scan (3 kernels): exclusive prefix over cnt -> row_ptr -------
__global__ __launch_bounds__(256) void k_scan1(const int* __restrict__ cnt,
    int* __restrict__ excl, int* __restrict__ bsum) {
  __shared__ int sd[256];
  int t = threadIdx.x;
  int i = blockIdx.x * 256 + t;
  int v = (i < N_NODES) ? cnt[i] : 0;
  sd[t] = v;
  __syncthreads();
#pragma unroll
  for (int off = 1; off < 256; off <<= 1) {
    int a = (t >= off) ? sd[t - off] : 0;
    __syncthreads();
    sd[t] += a;
    __syncthreads();
  }
  if (i < N_NODES) excl[i] = sd[t] - v;
  if (t == 255) bsum[blockIdx.x] = sd[255];
}

__global__ __launch_bounds__(256) void k_scan2(const int* __restrict__ bsum,
    int* __restrict__ boff, int nb, int* __restrict__ row_ptr_end) {
  __shared__ int sd[256];
  int t = threadIdx.x;
  int v = (t < nb) ? bsum[t] : 0;
  sd[t] = v;
  __syncthreads();
#pragma unroll
  for (int off = 1; off < 256; off <<= 1) {
    int a = (t >= off) ? sd[t - off] : 0;
    __syncthreads();
    sd[t] += a;
    __syncthreads();
  }
  boff[t] = sd[t] - v;
  if (t == 255) *row_ptr_end = sd[255];
}

__global__ __launch_bounds__(256) void k_scan3(int* __restrict__ row_ptr,
    const int* __restrict__ boff) {
  int i = blockIdx.x * 256 + threadIdx.x;
  if (i < N_NODES) row_ptr[i] += boff[blockIdx.x];
}

// ---------------- Kernel D: scatter edges into CSR order -----------------------
__global__ __launch_bounds__(256) void k_scatter(const int* __restrict__ ei,
    const float* __restrict__ w, const int* __restrict__ row_ptr,
    int* __restrict__ fill, int2* __restrict__ edata) {
  int e = blockIdx.x * 256 + threadIdx.x;
  if (e >= N_EDGES) return;
  int row = ei[e], col = ei[N_EDGES + e];
  int p = row_ptr[row] + atomicAdd(&fill[row], 1);
  edata[p] = make_int2(col, __float_as_int(w[e]));
}

// ---------------- Kernel E: agg1 (gather, unroll 8) + ReLU + h2 = h1_out @ W2 --
__global__ __launch_bounds__(256) void k_agg1(const float* __restrict__ h1,
    const int2* __restrict__ edata, const int* __restrict__ row_ptr,
    const float* __restrict__ W2, float* __restrict__ h2) {
  __shared__ float W2s[NHID * NCLASS];  // 10 KB
  __shared__ float accs[4][NHID];
  for (int i = threadIdx.x; i < NHID * NCLASS; i += 256) W2s[i] = W2[i];
  int wave = threadIdx.x >> 6, lane = threadIdx.x & 63;
  int r = blockIdx.x * 4 + wave;
  int start = row_ptr[r], end = row_ptr[r + 1];
  float acc = 0.f;
  int p = start;
  for (; p + 7 < end; p += 8) {
    int2 e0 = edata[p], e1 = edata[p + 1], e2 = edata[p + 2], e3 = edata[p + 3];
    int2 e4 = edata[p + 4], e5 = edata[p + 5], e6 = edata[p + 6], e7 = edata[p + 7];
    float v0 = h1[e0.x * NHID + lane];
    float v1 = h1[e1.x * NHID + lane];
    float v2 = h1[e2.x * NHID + lane];
    float v3 = h1[e3.x * NHID + lane];
    float v4 = h1[e4.x * NHID + lane];
    float v5 = h1[e5.x * NHID + lane];
    float v6 = h1[e6.x * NHID + lane];
    float v7 = h1[e7.x * NHID + lane];
    acc = fmaf(__int_as_float(e0.y), v0, acc);
    acc = fmaf(__int_as_float(e1.y), v1, acc);
    acc = fmaf(__int_as_float(e2.y), v2, acc);
    acc = fmaf(__int_as_float(e3.y), v3, acc);
    acc = fmaf(__int_as_float(e4.y), v4, acc);
    acc = fmaf(__int_as_float(e5.y), v5, acc);
    acc = fmaf(__int_as_float(e6.y), v6, acc);
    acc = fmaf(__int_as_float(e7.y), v7, acc);
  }
  for (; p + 3 < end; p += 4) {
    int2 e0 = edata[p], e1 = edata[p + 1], e2 = edata[p + 2], e3 = edata[p + 3];
    float v0 = h1[e0.x * NHID + lane];
    float v1 = h1[e1.x * NHID + lane];
    float v2 = h1[e2.x * NHID + lane];
    float v3 = h1[e3.x * NHID + lane];
    acc = fmaf(__int_as_float(e0.y), v0, acc);
    acc = fmaf(__int_as_float(e1.y), v1, acc);
    acc = fmaf(__int_as_float(e2.y), v2, acc);
    acc = fmaf(__int_as_float(e3.y), v3, acc);
  }
  for (; p < end; ++p) {
    int2 ed = edata[p];
    acc = fmaf(__int_as_float(ed.y), h1[ed.x * NHID + lane], acc);
  }
  accs[wave][lane] = fmaxf(acc, 0.f);   // ReLU(h1_out)
  __syncthreads();
  if (lane < NCLASS) {
    float s = 0.f;
#pragma unroll
    for (int j = 0; j < NHID; ++j)
      s = fmaf(accs[wave][j], W2s[j * NCLASS + lane], s);
    h2[r * NCLASS + lane] = s;
  }
}

// ---------------- Kernel F: agg2 (gather, unroll 4) + ReLU + res + LayerNorm ---
__global__ __launch_bounds__(256) void k_agg2(const float* __restrict__ h2,
    const int2* __restrict__ edata, const int* __restrict__ row_ptr,
    const float* __restrict__ res, const float* __restrict__ ln_g,
    const float* __restrict__ ln_b, float* __restrict__ out) {
  int wave = threadIdx.x >> 6, lane = threadIdx.x & 63;
  int r = blockIdx.x * 4 + wave;
  int start = row_ptr[r], end = row_ptr[r + 1];
  float y = 0.f;
  if (lane < NCLASS) {
    float acc = 0.f;
    int p = start;
    for (; p + 3 < end; p += 4) {
      int2 e0 = edata[p], e1 = edata[p + 1], e2 = edata[p + 2], e3 = edata[p + 3];
      float v0 = h2[e0.x * NCLASS + lane];
      float v1 = h2[e1.x * NCLASS + lane];
      float v2 = h2[e2.x * NCLASS + lane];
      float v3 = h2[e3.x * NCLASS + lane];
      acc = fmaf(__int_as_float(e0.y), v0, acc);
      acc = fmaf(__int_as_float(e1.y), v1, acc);
      acc = fmaf(__int_as_float(e2.y), v2, acc);
      acc = fmaf(__int_as_float(e3.y), v3, acc);
    }
    for (; p < end; ++p) {
      int2 ed = edata[p];
      acc = fmaf(__int_as_float(ed.y), h2[ed.x * NCLASS + lane], acc);
    }
    y = fmaxf(acc, 0.f) + res[r * NCLASS + lane];
  }
  // LayerNorm over 40 classes (lanes >= 40 contribute 0)
  float s1 = y, s2 = y * y;
#pragma unroll
  for (int off = 32; off; off >>= 1) {
    s1 += __shfl_xor(s1, off);
    s2 += __shfl_xor(s2, off);
  }
  float mu = s1 / (float)NCLASS;
  float var = s2 / (float)NCLASS - mu * mu;
  float inv = rsqrtf(var + LN_EPS);
  if (lane < NCLASS)
    out[r * NCLASS + lane] = (y - mu) * inv * ln_g[lane] + ln_b[lane];
}

// -------------------------------------------------------------------------------
extern "C" void kernel_launch(void* const* d_in, const int* in_sizes, int n_in,
                              void* d_out, int out_size, void* d_ws, size_t ws_size,
                              hipStream_t stream) {
  const float* x     = (const float*)d_in[0];
  const int*   ei    = (const int*)  d_in[1];
  const float* adj   = (const float*)d_in[2];
  const float* W1    = (const float*)d_in[3];
  const float* a1    = (const float*)d_in[4];
  const float* W2    = (const float*)d_in[5];
  const float* res_w = (const float*)d_in[6];
  const float* res_b = (const float*)d_in[7];
  const float* ln_g  = (const float*)d_in[8];
  const float* ln_b  = (const float*)d_in[9];
  float* out = (float*)d_out;

  char* ws = (char*)d_ws;
  size_t off = 0;
  auto alloc = [&](size_t bytes) -> void* {
    void* p = (void*)(ws + off);
    off += (bytes + 255) & ~(size_t)255;
    return p;
  };

  float* h1       = (float*)alloc((size_t)N_NODES * NHID * 4);
  float* s_src    = (float*)alloc((size_t)N_NODES * 4);
  float* s_dst    = (float*)alloc((size_t)N_NODES * 4);
  float* w        = (float*)alloc((size_t)N_EDGES * 4);
  int*   cnt      = (int*)  alloc((size_t)N_NODES * 4);
  int*   row_ptr  = (int*)  alloc((size_t)(N_NODES + 1) * 4);
  int*   bsum     = (int*)  alloc(256 * 4);
  int*   boff     = (int*)  alloc(256 * 4);
  int2*  edata    = (int2*) alloc((size_t)N_EDGES * 8);
  float* h2       = (float*)alloc((size_t)N_NODES * NCLASS * 4);
  float* res      = (float*)alloc((size_t)N_NODES * NCLASS * 4);
  (void)ws_size; (void)in_sizes; (void)n_in; (void)out_size;

  const int NBLK_NODE = N_NODES / 4;            // 12500 (exact)
  const int NBLK_EDGE = (N_EDGES + 255) / 256;  // 3125 (exact)
  const int NBLK_SCAN = (N_NODES + 255) / 256;  // 196
  const int NBLK_H1   = (N_NODES + 63) / 64;    // 782
  const int NBLK_RES  = (N_NODES + 127) / 128;  // 391

  hipMemsetAsync(cnt, 0, (size_t)N_NODES * 4, stream);
  k_h1mm<<<NBLK_H1, 256, 0, stream>>>(x, W1, a1, h1, s_src, s_dst);
  k_resmm<<<NBLK_RES, 256, 0, stream>>>(x, res_w, res_b, res);
  k_edge<<<NBLK_EDGE, 256, 0, stream>>>(ei, adj, s_src, s_dst, w, cnt);
  k_scan1<<<NBLK_SCAN, 256, 0, stream>>>(cnt, row_ptr, bsum);
  k_scan2<<<1, 256, 0, stream>>>(bsum, boff, NBLK_SCAN, row_ptr + N_NODES);
  k_scan3<<<NBLK_SCAN, 256, 0, stream>>>(row_ptr, boff);
  hipMemsetAsync(cnt, 0, (size_t)N_NODES * 4, stream);
  k_scatter<<<NBLK_EDGE, 256, 0, stream>>>(ei, w, row_ptr, cnt, edata);
  k_agg1<<<NBLK_NODE, 256, 0, stream>>>(h1, edata, row_ptr, W2, h2);
  k_agg2<<<NBLK_NODE, 256, 0, stream>>>(h2, edata, row_ptr, res, ln_g, ln_b, out);
}

// Round 4
// 228.349 us; speedup vs baseline: 1.8436x; 1.1076x over previous
//
#include <hip/hip_runtime.h>
#include <math.h>

#define N_NODES 50000
#define N_EDGES 800000
#define NFEAT 128
#define NHID 64
#define NCLASS 40
#define LN_EPS 1e-5f

__device__ __forceinline__ int swz(int k) { return ((k >> 2) & 7) << 2; }

// pack two f32 -> two bf16 (RNE) in one uint
__device__ __forceinline__ unsigned packbf(float a, float b) {
  unsigned ua = __float_as_uint(a), ub = __float_as_uint(b);
  ua += 0x7fffu + ((ua >> 16) & 1u);
  ub += 0x7fffu + ((ub >> 16) & 1u);
  return (ua >> 16) | (ub & 0xffff0000u);
}
__device__ __forceinline__ float lo16(unsigned v) { return __uint_as_float(v << 16); }
__device__ __forceinline__ float hi16(unsigned v) { return __uint_as_float(v & 0xffff0000u); }

// ------ Kernel A: h1 = x @ W1 (reg-blocked 4x4) + fused s_src/s_dst ------------
// h1 stored as packed bf16 (uint = 2 cols)
__global__ __launch_bounds__(256) void k_h1mm(const float* __restrict__ x,
    const float* __restrict__ W1, const float* __restrict__ a1,
    unsigned* __restrict__ h1u, float* __restrict__ s_src, float* __restrict__ s_dst) {
  __shared__ float xT[NFEAT * 64];    // [k][r ^ swz(k)]  32 KB
  __shared__ float W1s[NFEAT * NHID]; // [k][c]           32 KB
  int t = threadIdx.x;
  int R0 = blockIdx.x * 64;
  for (int i = t; i < NFEAT * NHID / 4; i += 256)
    ((float4*)W1s)[i] = ((const float4*)W1)[i];
#pragma unroll
  for (int it = 0; it < 8; ++it) {
    int i = t + it * 256;
    int r = i >> 5, kq = i & 31;
    int gr = R0 + r;
    float4 v = make_float4(0.f, 0.f, 0.f, 0.f);
    if (gr < N_NODES) v = *(const float4*)(x + (size_t)gr * NFEAT + kq * 4);
    int rw = r ^ ((kq & 7) << 2);
    xT[(kq * 4 + 0) * 64 + rw] = v.x;
    xT[(kq * 4 + 1) * 64 + rw] = v.y;
    xT[(kq * 4 + 2) * 64 + rw] = v.z;
    xT[(kq * 4 + 3) * 64 + rw] = v.w;
  }
  __syncthreads();
  int cg = t & 15, rg = t >> 4;
  int c0 = cg * 4, r0 = rg * 4;
  float acc[4][4] = {};
#pragma unroll 4
  for (int k = 0; k < NFEAT; ++k) {
    float4 xv = *(const float4*)&xT[k * 64 + (r0 ^ swz(k))];
    float4 wv = *(const float4*)&W1s[k * NHID + c0];
    float xr[4] = {xv.x, xv.y, xv.z, xv.w};
    float wr[4] = {wv.x, wv.y, wv.z, wv.w};
#pragma unroll
    for (int j = 0; j < 4; ++j)
#pragma unroll
      for (int c = 0; c < 4; ++c)
        acc[j][c] = fmaf(xr[j], wr[c], acc[j][c]);
  }
  float4 as = *(const float4*)(a1 + c0);
  float4 ad = *(const float4*)(a1 + NHID + c0);
  float asr[4] = {as.x, as.y, as.z, as.w};
  float adr[4] = {ad.x, ad.y, ad.z, ad.w};
  float ps[4], pd[4];
#pragma unroll
  for (int j = 0; j < 4; ++j) {
    int gr = R0 + r0 + j;
    if (gr < N_NODES) {
      uint2 pk;
      pk.x = packbf(acc[j][0], acc[j][1]);
      pk.y = packbf(acc[j][2], acc[j][3]);
      *(uint2*)&h1u[(size_t)gr * 32 + (c0 >> 1)] = pk;
    }
    float s = 0.f, d = 0.f;
#pragma unroll
    for (int c = 0; c < 4; ++c) {
      s = fmaf(acc[j][c], asr[c], s);
      d = fmaf(acc[j][c], adr[c], d);
    }
    ps[j] = s; pd[j] = d;
  }
#pragma unroll
  for (int j = 0; j < 4; ++j)
#pragma unroll
    for (int off = 1; off < 16; off <<= 1) {
      ps[j] += __shfl_xor(ps[j], off);
      pd[j] += __shfl_xor(pd[j], off);
    }
  if (cg == 0) {
#pragma unroll
    for (int j = 0; j < 4; ++j) {
      int gr = R0 + r0 + j;
      if (gr < N_NODES) { s_src[gr] = ps[j]; s_dst[gr] = pd[j]; }
    }
  }
}

// ------ Kernel R: res = x @ res_w^T + res_b (reg-blocked 4x5, f32) -------------
__global__ __launch_bounds__(256) void k_resmm(const float* __restrict__ x,
    const float* __restrict__ res_w, const float* __restrict__ res_b,
    float* __restrict__ res) {
  __shared__ float xT[NFEAT * 128];     // 64 KB
  __shared__ float rwT[NFEAT * NCLASS]; // 20 KB
  int t = threadIdx.x;
  int R0 = blockIdx.x * 128;
  for (int i = t; i < NCLASS * NFEAT; i += 256) {
    int c = i / NFEAT, k = i % NFEAT;
    rwT[k * NCLASS + c] = res_w[i];
  }
#pragma unroll
  for (int it = 0; it < 16; ++it) {
    int i = t + it * 256;
    int r = i >> 5, kq = i & 31;
    int gr = R0 + r;
    float4 v = make_float4(0.f, 0.f, 0.f, 0.f);
    if (gr < N_NODES) v = *(const float4*)(x + (size_t)gr * NFEAT + kq * 4);
    int rw = r ^ ((kq & 7) << 2);
    xT[(kq * 4 + 0) * 128 + rw] = v.x;
    xT[(kq * 4 + 1) * 128 + rw] = v.y;
    xT[(kq * 4 + 2) * 128 + rw] = v.z;
    xT[(kq * 4 + 3) * 128 + rw] = v.w;
  }
  __syncthreads();
  int cg = t & 7, rg = t >> 3;
  int c0 = cg * 5, r0 = rg * 4;
  float acc[4][5] = {};
#pragma unroll 4
  for (int k = 0; k < NFEAT; ++k) {
    float4 xv = *(const float4*)&xT[k * 128 + (r0 ^ swz(k))];
    float xr[4] = {xv.x, xv.y, xv.z, xv.w};
    float wr[5];
#pragma unroll
    for (int c = 0; c < 5; ++c) wr[c] = rwT[k * NCLASS + c0 + c];
#pragma unroll
    for (int j = 0; j < 4; ++j)
#pragma unroll
      for (int c = 0; c < 5; ++c)
        acc[j][c] = fmaf(xr[j], wr[c], acc[j][c]);
  }
  float bb[5];
#pragma unroll
  for (int c = 0; c < 5; ++c) bb[c] = res_b[c0 + c];
#pragma unroll
  for (int j = 0; j < 4; ++j) {
    int gr = R0 + r0 + j;
    if (gr < N_NODES) {
#pragma unroll
      for (int c = 0; c < 5; ++c)
        res[(size_t)gr * NCLASS + c0 + c] = acc[j][c] + bb[c];
    }
  }
}

// ---------------- Kernel B: row histogram only ---------------------------------
__global__ __launch_bounds__(256) void k_hist(const int* __restrict__ ei,
    int* __restrict__ cnt) {
  int e = blockIdx.x * 256 + threadIdx.x;
  if (e >= N_EDGES) return;
  atomicAdd(&cnt[ei[e]], 1);
}

// ---------------- Scan (3 kernels): exclusive prefix over cnt -> row_ptr -------
__global__ __launch_bounds__(256) void k_scan1(const int* __restrict__ cnt,
    int* __restrict__ excl, int* __restrict__ bsum) {
  __shared__ int sd[256];
  int t = threadIdx.x;
  int i = blockIdx.x * 256 + t;
  int v = (i < N_NODES) ? cnt[i] : 0;
  sd[t] = v;
  __syncthreads();
#pragma unroll
  for (int off = 1; off < 256; off <<= 1) {
    int a = (t >= off) ? sd[t - off] : 0;
    __syncthreads();
    sd[t] += a;
    __syncthreads();
  }
  if (i < N_NODES) excl[i] = sd[t] - v;
  if (t == 255) bsum[blockIdx.x] = sd[255];
}

__global__ __launch_bounds__(256) void k_scan2(const int* __restrict__ bsum,
    int* __restrict__ boff, int nb, int* __restrict__ row_ptr_end) {
  __shared__ int sd[256];
  int t = threadIdx.x;
  int v = (t < nb) ? bsum[t] : 0;
  sd[t] = v;
  __syncthreads();
#pragma unroll
  for (int off = 1; off < 256; off <<= 1) {
    int a = (t >= off) ? sd[t - off] : 0;
    __syncthreads();
    sd[t] += a;
    __syncthreads();
  }
  boff[t] = sd[t] - v;
  if (t == 255) *row_ptr_end = sd[255];
}

__global__ __launch_bounds__(256) void k_scan3(int* __restrict__ row_ptr,
    const int* __restrict__ boff) {
  int i = blockIdx.x * 256 + threadIdx.x;
  if (i < N_NODES) row_ptr[i] += boff[blockIdx.x];
}

// ---------------- Kernel D: edge weights + scatter into CSR order --------------
__global__ __launch_bounds__(256) void k_scatter(const int* __restrict__ ei,
    const float* __restrict__ adj, const float* __restrict__ s_src,
    const float* __restrict__ s_dst, const int* __restrict__ row_ptr,
    int* __restrict__ fill, int2* __restrict__ edata) {
  int e = blockIdx.x * 256 + threadIdx.x;
  if (e >= N_EDGES) return;
  int row = ei[e], col = ei[N_EDGES + e];
  int p = row_ptr[row] + atomicAdd(&fill[row], 1);
  float s = s_src[row] + s_dst[col];
  s = (s > 0.f) ? s : 0.2f * s;                 // leaky_relu(0.2)
  float wv = adj[e] / (1.f + __expf(-s));       // sigmoid * adj
  edata[p] = make_int2(col, __float_as_int(wv));
}

// ------ Kernel E: agg1 (bf16 gather, 2 edge-groups) + ReLU + h2 = h1_out @ W2 --
__global__ __launch_bounds__(256) void k_agg1(const unsigned* __restrict__ h1u,
    const int2* __restrict__ edata, const int* __restrict__ row_ptr,
    const float* __restrict__ W2, unsigned* __restrict__ h2u) {
  __shared__ float W2s[NHID * NCLASS];  // 10 KB
  __shared__ float accs[4][NHID];
  for (int i = threadIdx.x; i < NHID * NCLASS; i += 256) W2s[i] = W2[i];
  int wave = threadIdx.x >> 6, lane = threadIdx.x & 63;
  int g = lane >> 5, s = lane & 31;
  int r = blockIdx.x * 4 + wave;
  int start = row_ptr[r], end = row_ptr[r + 1];
  float acc0 = 0.f, acc1 = 0.f;
  int p = start + g;                 // group g takes every other edge
  for (; p + 6 < end; p += 8) {
    int2 e0 = edata[p], e1 = edata[p + 2], e2 = edata[p + 4], e3 = edata[p + 6];
    unsigned v0 = h1u[(size_t)e0.x * 32 + s];
    unsigned v1 = h1u[(size_t)e1.x * 32 + s];
    unsigned v2 = h1u[(size_t)e2.x * 32 + s];
    unsigned v3 = h1u[(size_t)e3.x * 32 + s];
    float w0 = __int_as_float(e0.y), w1 = __int_as_float(e1.y);
    float w2 = __int_as_float(e2.y), w3 = __int_as_float(e3.y);
    acc0 = fmaf(w0, lo16(v0), acc0); acc1 = fmaf(w0, hi16(v0), acc1);
    acc0 = fmaf(w1, lo16(v1), acc0); acc1 = fmaf(w1, hi16(v1), acc1);
    acc0 = fmaf(w2, lo16(v2), acc0); acc1 = fmaf(w2, hi16(v2), acc1);
    acc0 = fmaf(w3, lo16(v3), acc0); acc1 = fmaf(w3, hi16(v3), acc1);
  }
  for (; p < end; p += 2) {
    int2 ed = edata[p];
    unsigned v = h1u[(size_t)ed.x * 32 + s];
    float wv = __int_as_float(ed.y);
    acc0 = fmaf(wv, lo16(v), acc0); acc1 = fmaf(wv, hi16(v), acc1);
  }
  acc0 += __shfl_xor(acc0, 32);
  acc1 += __shfl_xor(acc1, 32);
  if (g == 0)
    *(float2*)&accs[wave][2 * s] = make_float2(fmaxf(acc0, 0.f), fmaxf(acc1, 0.f));
  __syncthreads();
  float sv = 0.f;
  if (lane < NCLASS) {
#pragma unroll
    for (int j = 0; j < NHID; ++j)
      sv = fmaf(accs[wave][j], W2s[j * NCLASS + lane], sv);
  }
  float nxt = __shfl_down(sv, 1);
  if (lane < NCLASS && !(lane & 1))
    h2u[(size_t)r * 20 + (lane >> 1)] = packbf(sv, nxt);
}

// ------ Kernel F: agg2 (bf16 gather, 2 edge-groups) + ReLU + res + LayerNorm ---
__global__ __launch_bounds__(256) void k_agg2(const unsigned* __restrict__ h2u,
    const int2* __restrict__ edata, const int* __restrict__ row_ptr,
    const float* __restrict__ res, const float* __restrict__ ln_g,
    const float* __restrict__ ln_b, float* __restrict__ out) {
  int wave = threadIdx.x >> 6, lane = threadIdx.x & 63;
  int g = lane >> 5, s = lane & 31;
  int r = blockIdx.x * 4 + wave;
  int start = row_ptr[r], end = row_ptr[r + 1];
  float acc0 = 0.f, acc1 = 0.f;
  int p = start + g;
  for (; p + 6 < end; p += 8) {
    int2 e0 = edata[p], e1 = edata[p + 2], e2 = edata[p + 4], e3 = edata[p + 6];
    unsigned v0 = 0, v1 = 0, v2 = 0, v3 = 0;
    if (s < 20) {
      v0 = h2u[(size_t)e0.x * 20 + s];
      v1 = h2u[(size_t)e1.x * 20 + s];
      v2 = h2u[(size_t)e2.x * 20 + s];
      v3 = h2u[(size_t)e3.x * 20 + s];
    }
    float w0 = __int_as_float(e0.y), w1 = __int_as_float(e1.y);
    float w2 = __int_as_float(e2.y), w3 = __int_as_float(e3.y);
    acc0 = fmaf(w0, lo16(v0), acc0); acc1 = fmaf(w0, hi16(v0), acc1);
    acc0 = fmaf(w1, lo16(v1), acc0); acc1 = fmaf(w1, hi16(v1), acc1);
    acc0 = fmaf(w2, lo16(v2), acc0); acc1 = fmaf(w2, hi16(v2), acc1);
    acc0 = fmaf(w3, lo16(v3), acc0); acc1 = fmaf(w3, hi16(v3), acc1);
  }
  for (; p < end; p += 2) {
    int2 ed = edata[p];
    unsigned v = (s < 20) ? h2u[(size_t)ed.x * 20 + s] : 0u;
    float wv = __int_as_float(ed.y);
    acc0 = fmaf(wv, lo16(v), acc0); acc1 = fmaf(wv, hi16(v), acc1);
  }
  acc0 += __shfl_xor(acc0, 32);
  acc1 += __shfl_xor(acc1, 32);
  float yl = 0.f, yh = 0.f;
  if (g == 0 && s < 20) {
    float2 rv = *(const float2*)(res + (size_t)r * NCLASS + 2 * s);
    yl = fmaxf(acc0, 0.f) + rv.x;
    yh = fmaxf(acc1, 0.f) + rv.y;
  }
  float s1 = yl + yh, s2 = yl * yl + yh * yh;
#pragma unroll
  for (int off = 1; off < 32; off <<= 1) {
    s1 += __shfl_xor(s1, off);
    s2 += __shfl_xor(s2, off);
  }
  float mu = s1 / (float)NCLASS;
  float var = s2 / (float)NCLASS - mu * mu;
  float inv = rsqrtf(var + LN_EPS);
  if (g == 0 && s < 20) {
    float2 gv = *(const float2*)(ln_g + 2 * s);
    float2 bv = *(const float2*)(ln_b + 2 * s);
    float2 o;
    o.x = (yl - mu) * inv * gv.x + bv.x;
    o.y = (yh - mu) * inv * gv.y + bv.y;
    *(float2*)(out + (size_t)r * NCLASS + 2 * s) = o;
  }
}

// -------------------------------------------------------------------------------
extern "C" void kernel_launch(void* const* d_in, const int* in_sizes, int n_in,
                              void* d_out, int out_size, void* d_ws, size_t ws_size,
                              hipStream_t stream) {
  const float* x     = (const float*)d_in[0];
  const int*   ei    = (const int*)  d_in[1];
  const float* adj   = (const float*)d_in[2];
  const float* W1    = (const float*)d_in[3];
  const float* a1    = (const float*)d_in[4];
  const float* W2    = (const float*)d_in[5];
  const float* res_w = (const float*)d_in[6];
  const float* res_b = (const float*)d_in[7];
  const float* ln_g  = (const float*)d_in[8];
  const float* ln_b  = (const float*)d_in[9];
  float* out = (float*)d_out;

  char* ws = (char*)d_ws;
  size_t off = 0;
  auto alloc = [&](size_t bytes) -> void* {
    void* p = (void*)(ws + off);
    off += (bytes + 255) & ~(size_t)255;
    return p;
  };

  unsigned* h1u     = (unsigned*)alloc((size_t)N_NODES * 32 * 4);  // bf16x2 packed
  float*    s_src   = (float*)alloc((size_t)N_NODES * 4);
  float*    s_dst   = (float*)alloc((size_t)N_NODES * 4);
  int*      cnt     = (int*)  alloc((size_t)N_NODES * 4);
  int*      row_ptr = (int*)  alloc((size_t)(N_NODES + 1) * 4);
  int*      bsum    = (int*)  alloc(256 * 4);
  int*      boff    = (int*)  alloc(256 * 4);
  int2*     edata   = (int2*) alloc((size_t)N_EDGES * 8);
  unsigned* h2u     = (unsigned*)alloc((size_t)N_NODES * 20 * 4);  // bf16x2 packed
  float*    res     = (float*)alloc((size_t)N_NODES * NCLASS * 4);
  (void)ws_size; (void)in_sizes; (void)n_in; (void)out_size;

  const int NBLK_NODE = N_NODES / 4;            // 12500
  const int NBLK_EDGE = (N_EDGES + 255) / 256;  // 3125
  const int NBLK_SCAN = (N_NODES + 255) / 256;  // 196
  const int NBLK_H1   = (N_NODES + 63) / 64;    // 782
  const int NBLK_RES  = (N_NODES + 127) / 128;  // 391

  hipMemsetAsync(cnt, 0, (size_t)N_NODES * 4, stream);
  k_h1mm<<<NBLK_H1, 256, 0, stream>>>(x, W1, a1, h1u, s_src, s_dst);
  k_resmm<<<NBLK_RES, 256, 0, stream>>>(x, res_w, res_b, res);
  k_hist<<<NBLK_EDGE, 256, 0, stream>>>(ei, cnt);
  k_scan1<<<NBLK_SCAN, 256, 0, stream>>>(cnt, row_ptr, bsum);
  k_scan2<<<1, 256, 0, stream>>>(bsum, boff, NBLK_SCAN, row_ptr + N_NODES);
  k_scan3<<<NBLK_SCAN, 256, 0, stream>>>(row_ptr, boff);
  hipMemsetAsync(cnt, 0, (size_t)N_NODES * 4, stream);
  k_scatter<<<NBLK_EDGE, 256, 0, stream>>>(ei, adj, s_src, s_dst, row_ptr, cnt, edata);
  k_agg1<<<NBLK_NODE, 256, 0, stream>>>(h1u, edata, row_ptr, W2, h2u);
  k_agg2<<<NBLK_NODE, 256, 0, stream>>>(h2u, edata, row_ptr, res, ln_g, ln_b, out);
}

// Round 5
// 221.890 us; speedup vs baseline: 1.8973x; 1.0291x over previous
//
#include <hip/hip_runtime.h>
#include <math.h>

#define N_NODES 50000
#define N_EDGES 800000
#define NFEAT 128
#define NHID 64
#define NCLASS 40
#define LN_EPS 1e-5f

__device__ __forceinline__ int swz(int k) { return ((k >> 2) & 7) << 2; }

// pack two f32 -> two bf16 (RNE) in one uint
__device__ __forceinline__ unsigned packbf(float a, float b) {
  unsigned ua = __float_as_uint(a), ub = __float_as_uint(b);
  ua += 0x7fffu + ((ua >> 16) & 1u);
  ub += 0x7fffu + ((ub >> 16) & 1u);
  return (ua >> 16) | (ub & 0xffff0000u);
}
__device__ __forceinline__ unsigned bf16hi(float a) {  // bf16(a) in top 16 bits
  unsigned u = __float_as_uint(a);
  u += 0x7fffu + ((u >> 16) & 1u);
  return u & 0xffff0000u;
}
__device__ __forceinline__ float lo16(unsigned v) { return __uint_as_float(v << 16); }
__device__ __forceinline__ float hi16(unsigned v) { return __uint_as_float(v & 0xffff0000u); }

// ------ Kernel A: h1 = x @ W1 (reg-blocked 4x4) + fused s_src/s_dst ------------
__global__ __launch_bounds__(256) void k_h1mm(const float* __restrict__ x,
    const float* __restrict__ W1, const float* __restrict__ a1,
    unsigned* __restrict__ h1u, float* __restrict__ s_src, float* __restrict__ s_dst) {
  __shared__ float xT[NFEAT * 64];    // 32 KB
  __shared__ float W1s[NFEAT * NHID]; // 32 KB
  int t = threadIdx.x;
  int R0 = blockIdx.x * 64;
  for (int i = t; i < NFEAT * NHID / 4; i += 256)
    ((float4*)W1s)[i] = ((const float4*)W1)[i];
#pragma unroll
  for (int it = 0; it < 8; ++it) {
    int i = t + it * 256;
    int r = i >> 5, kq = i & 31;
    int gr = R0 + r;
    float4 v = make_float4(0.f, 0.f, 0.f, 0.f);
    if (gr < N_NODES) v = *(const float4*)(x + (size_t)gr * NFEAT + kq * 4);
    int rw = r ^ ((kq & 7) << 2);
    xT[(kq * 4 + 0) * 64 + rw] = v.x;
    xT[(kq * 4 + 1) * 64 + rw] = v.y;
    xT[(kq * 4 + 2) * 64 + rw] = v.z;
    xT[(kq * 4 + 3) * 64 + rw] = v.w;
  }
  __syncthreads();
  int cg = t & 15, rg = t >> 4;
  int c0 = cg * 4, r0 = rg * 4;
  float acc[4][4] = {};
#pragma unroll 4
  for (int k = 0; k < NFEAT; ++k) {
    float4 xv = *(const float4*)&xT[k * 64 + (r0 ^ swz(k))];
    float4 wv = *(const float4*)&W1s[k * NHID + c0];
    float xr[4] = {xv.x, xv.y, xv.z, xv.w};
    float wr[4] = {wv.x, wv.y, wv.z, wv.w};
#pragma unroll
    for (int j = 0; j < 4; ++j)
#pragma unroll
      for (int c = 0; c < 4; ++c)
        acc[j][c] = fmaf(xr[j], wr[c], acc[j][c]);
  }
  float4 as = *(const float4*)(a1 + c0);
  float4 ad = *(const float4*)(a1 + NHID + c0);
  float asr[4] = {as.x, as.y, as.z, as.w};
  float adr[4] = {ad.x, ad.y, ad.z, ad.w};
  float ps[4], pd[4];
#pragma unroll
  for (int j = 0; j < 4; ++j) {
    int gr = R0 + r0 + j;
    if (gr < N_NODES) {
      uint2 pk;
      pk.x = packbf(acc[j][0], acc[j][1]);
      pk.y = packbf(acc[j][2], acc[j][3]);
      *(uint2*)&h1u[(size_t)gr * 32 + (c0 >> 1)] = pk;
    }
    float s = 0.f, d = 0.f;
#pragma unroll
    for (int c = 0; c < 4; ++c) {
      s = fmaf(acc[j][c], asr[c], s);
      d = fmaf(acc[j][c], adr[c], d);
    }
    ps[j] = s; pd[j] = d;
  }
#pragma unroll
  for (int j = 0; j < 4; ++j)
#pragma unroll
    for (int off = 1; off < 16; off <<= 1) {
      ps[j] += __shfl_xor(ps[j], off);
      pd[j] += __shfl_xor(pd[j], off);
    }
  if (cg == 0) {
#pragma unroll
    for (int j = 0; j < 4; ++j) {
      int gr = R0 + r0 + j;
      if (gr < N_NODES) { s_src[gr] = ps[j]; s_dst[gr] = pd[j]; }
    }
  }
}

// ------ Kernel R: res = x @ res_w^T + res_b (reg-blocked 4x5, f32) -------------
__global__ __launch_bounds__(256) void k_resmm(const float* __restrict__ x,
    const float* __restrict__ res_w, const float* __restrict__ res_b,
    float* __restrict__ res) {
  __shared__ float xT[NFEAT * 128];     // 64 KB
  __shared__ float rwT[NFEAT * NCLASS]; // 20 KB
  int t = threadIdx.x;
  int R0 = blockIdx.x * 128;
  for (int i = t; i < NCLASS * NFEAT; i += 256) {
    int c = i / NFEAT, k = i % NFEAT;
    rwT[k * NCLASS + c] = res_w[i];
  }
#pragma unroll
  for (int it = 0; it < 16; ++it) {
    int i = t + it * 256;
    int r = i >> 5, kq = i & 31;
    int gr = R0 + r;
    float4 v = make_float4(0.f, 0.f, 0.f, 0.f);
    if (gr < N_NODES) v = *(const float4*)(x + (size_t)gr * NFEAT + kq * 4);
    int rw = r ^ ((kq & 7) << 2);
    xT[(kq * 4 + 0) * 128 + rw] = v.x;
    xT[(kq * 4 + 1) * 128 + rw] = v.y;
    xT[(kq * 4 + 2) * 128 + rw] = v.z;
    xT[(kq * 4 + 3) * 128 + rw] = v.w;
  }
  __syncthreads();
  int cg = t & 7, rg = t >> 3;
  int c0 = cg * 5, r0 = rg * 4;
  float acc[4][5] = {};
#pragma unroll 4
  for (int k = 0; k < NFEAT; ++k) {
    float4 xv = *(const float4*)&xT[k * 128 + (r0 ^ swz(k))];
    float xr[4] = {xv.x, xv.y, xv.z, xv.w};
    float wr[5];
#pragma unroll
    for (int c = 0; c < 5; ++c) wr[c] = rwT[k * NCLASS + c0 + c];
#pragma unroll
    for (int j = 0; j < 4; ++j)
#pragma unroll
      for (int c = 0; c < 5; ++c)
        acc[j][c] = fmaf(xr[j], wr[c], acc[j][c]);
  }
  float bb[5];
#pragma unroll
  for (int c = 0; c < 5; ++c) bb[c] = res_b[c0 + c];
#pragma unroll
  for (int j = 0; j < 4; ++j) {
    int gr = R0 + r0 + j;
    if (gr < N_NODES) {
#pragma unroll
      for (int c = 0; c < 5; ++c)
        res[(size_t)gr * NCLASS + c0 + c] = acc[j][c] + bb[c];
    }
  }
}

// ---------------- Kernel B: row histogram only ---------------------------------
__global__ __launch_bounds__(256) void k_hist(const int* __restrict__ ei,
    int* __restrict__ cnt) {
  int e = blockIdx.x * 256 + threadIdx.x;
  if (e >= N_EDGES) return;
  atomicAdd(&cnt[ei[e]], 1);
}

// ---------------- Scan (3 kernels): exclusive prefix over cnt -> row_ptr -------
__global__ __launch_bounds__(256) void k_scan1(const int* __restrict__ cnt,
    int* __restrict__ excl, int* __restrict__ bsum) {
  __shared__ int sd[256];
  int t = threadIdx.x;
  int i = blockIdx.x * 256 + t;
  int v = (i < N_NODES) ? cnt[i] : 0;
  sd[t] = v;
  __syncthreads();
#pragma unroll
  for (int off = 1; off < 256; off <<= 1) {
    int a = (t >= off) ? sd[t - off] : 0;
    __syncthreads();
    sd[t] += a;
    __syncthreads();
  }
  if (i < N_NODES) excl[i] = sd[t] - v;
  if (t == 255) bsum[blockIdx.x] = sd[255];
}

__global__ __launch_bounds__(256) void k_scan2(const int* __restrict__ bsum,
    int* __restrict__ boff, int nb, int* __restrict__ row_ptr_end) {
  __shared__ int sd[256];
  int t = threadIdx.x;
  int v = (t < nb) ? bsum[t] : 0;
  sd[t] = v;
  __syncthreads();
#pragma unroll
  for (int off = 1; off < 256; off <<= 1) {
    int a = (t >= off) ? sd[t - off] : 0;
    __syncthreads();
    sd[t] += a;
    __syncthreads();
  }
  boff[t] = sd[t] - v;
  if (t == 255) *row_ptr_end = sd[255];
}

__global__ __launch_bounds__(256) void k_scan3(int* __restrict__ row_ptr,
    const int* __restrict__ boff) {
  int i = blockIdx.x * 256 + threadIdx.x;
  if (i < N_NODES) row_ptr[i] += boff[blockIdx.x];
}

// ------ Kernel D: edge weights + scatter packed (col:16 | w:bf16:16) -----------
__global__ __launch_bounds__(256) void k_scatter(const int* __restrict__ ei,
    const float* __restrict__ adj, const float* __restrict__ s_src,
    const float* __restrict__ s_dst, const int* __restrict__ row_ptr,
    int* __restrict__ fill, unsigned* __restrict__ edata) {
  int e = blockIdx.x * 256 + threadIdx.x;
  if (e >= N_EDGES) return;
  int row = ei[e], col = ei[N_EDGES + e];
  int p = row_ptr[row] + atomicAdd(&fill[row], 1);
  float s = s_src[row] + s_dst[col];
  s = (s > 0.f) ? s : 0.2f * s;                 // leaky_relu(0.2)
  float wv = adj[e] / (1.f + __expf(-s));       // sigmoid * adj
  edata[p] = bf16hi(wv) | (unsigned)col;
}

// ------ Kernel E: agg1 (bf16 gather, 2 groups, unroll 8) + ReLU + W2 GEMM ------
__global__ __launch_bounds__(256) void k_agg1(const unsigned* __restrict__ h1u,
    const unsigned* __restrict__ edata, const int* __restrict__ row_ptr,
    const float* __restrict__ W2, unsigned* __restrict__ h2u) {
  __shared__ float W2s[NHID * NCLASS];  // 10 KB
  __shared__ float accs[4][NHID];
  for (int i = threadIdx.x; i < NHID * NCLASS; i += 256) W2s[i] = W2[i];
  int wave = threadIdx.x >> 6, lane = threadIdx.x & 63;
  int g = lane >> 5, s = lane & 31;
  int r = blockIdx.x * 4 + wave;
  int start = row_ptr[r], end = row_ptr[r + 1];
  float acc0 = 0.f, acc1 = 0.f;
  int p = start + g;                 // group g takes every other edge
  for (; p + 14 < end; p += 16) {    // 8 edges per group in flight
    unsigned u0 = edata[p],      u1 = edata[p + 2],  u2 = edata[p + 4],  u3 = edata[p + 6];
    unsigned u4 = edata[p + 8],  u5 = edata[p + 10], u6 = edata[p + 12], u7 = edata[p + 14];
    unsigned v0 = h1u[(size_t)(u0 & 0xffffu) * 32 + s];
    unsigned v1 = h1u[(size_t)(u1 & 0xffffu) * 32 + s];
    unsigned v2 = h1u[(size_t)(u2 & 0xffffu) * 32 + s];
    unsigned v3 = h1u[(size_t)(u3 & 0xffffu) * 32 + s];
    unsigned v4 = h1u[(size_t)(u4 & 0xffffu) * 32 + s];
    unsigned v5 = h1u[(size_t)(u5 & 0xffffu) * 32 + s];
    unsigned v6 = h1u[(size_t)(u6 & 0xffffu) * 32 + s];
    unsigned v7 = h1u[(size_t)(u7 & 0xffffu) * 32 + s];
    acc0 = fmaf(hi16(u0), lo16(v0), acc0); acc1 = fmaf(hi16(u0), hi16(v0), acc1);
    acc0 = fmaf(hi16(u1), lo16(v1), acc0); acc1 = fmaf(hi16(u1), hi16(v1), acc1);
    acc0 = fmaf(hi16(u2), lo16(v2), acc0); acc1 = fmaf(hi16(u2), hi16(v2), acc1);
    acc0 = fmaf(hi16(u3), lo16(v3), acc0); acc1 = fmaf(hi16(u3), hi16(v3), acc1);
    acc0 = fmaf(hi16(u4), lo16(v4), acc0); acc1 = fmaf(hi16(u4), hi16(v4), acc1);
    acc0 = fmaf(hi16(u5), lo16(v5), acc0); acc1 = fmaf(hi16(u5), hi16(v5), acc1);
    acc0 = fmaf(hi16(u6), lo16(v6), acc0); acc1 = fmaf(hi16(u6), hi16(v6), acc1);
    acc0 = fmaf(hi16(u7), lo16(v7), acc0); acc1 = fmaf(hi16(u7), hi16(v7), acc1);
  }
  for (; p + 6 < end; p += 8) {      // 4 edges per group
    unsigned u0 = edata[p], u1 = edata[p + 2], u2 = edata[p + 4], u3 = edata[p + 6];
    unsigned v0 = h1u[(size_t)(u0 & 0xffffu) * 32 + s];
    unsigned v1 = h1u[(size_t)(u1 & 0xffffu) * 32 + s];
    unsigned v2 = h1u[(size_t)(u2 & 0xffffu) * 32 + s];
    unsigned v3 = h1u[(size_t)(u3 & 0xffffu) * 32 + s];
    acc0 = fmaf(hi16(u0), lo16(v0), acc0); acc1 = fmaf(hi16(u0), hi16(v0), acc1);
    acc0 = fmaf(hi16(u1), lo16(v1), acc0); acc1 = fmaf(hi16(u1), hi16(v1), acc1);
    acc0 = fmaf(hi16(u2), lo16(v2), acc0); acc1 = fmaf(hi16(u2), hi16(v2), acc1);
    acc0 = fmaf(hi16(u3), lo16(v3), acc0); acc1 = fmaf(hi16(u3), hi16(v3), acc1);
  }
  for (; p < end; p += 2) {
    unsigned u = edata[p];
    unsigned v = h1u[(size_t)(u & 0xffffu) * 32 + s];
    acc0 = fmaf(hi16(u), lo16(v), acc0); acc1 = fmaf(hi16(u), hi16(v), acc1);
  }
  acc0 += __shfl_xor(acc0, 32);
  acc1 += __shfl_xor(acc1, 32);
  if (g == 0)
    *(float2*)&accs[wave][2 * s] = make_float2(fmaxf(acc0, 0.f), fmaxf(acc1, 0.f));
  __syncthreads();
  float sv = 0.f;
  if (lane < NCLASS) {
#pragma unroll
    for (int j = 0; j < NHID; ++j)
      sv = fmaf(accs[wave][j], W2s[j * NCLASS + lane], sv);
  }
  float nxt = __shfl_down(sv, 1);
  if (lane < NCLASS && !(lane & 1))
    h2u[(size_t)r * 20 + (lane >> 1)] = packbf(sv, nxt);
}

// ------ Kernel F: agg2 (bf16 gather, 2 groups, unroll 8) + res + LayerNorm -----
__global__ __launch_bounds__(256) void k_agg2(const unsigned* __restrict__ h2u,
    const unsigned* __restrict__ edata, const int* __restrict__ row_ptr,
    const float* __restrict__ res, const float* __restrict__ ln_g,
    const float* __restrict__ ln_b, float* __restrict__ out) {
  int wave = threadIdx.x >> 6, lane = threadIdx.x & 63;
  int g = lane >> 5, s = lane & 31;
  int r = blockIdx.x * 4 + wave;
  int start = row_ptr[r], end = row_ptr[r + 1];
  float acc0 = 0.f, acc1 = 0.f;
  int p = start + g;
  for (; p + 14 < end; p += 16) {
    unsigned u0 = edata[p],      u1 = edata[p + 2],  u2 = edata[p + 4],  u3 = edata[p + 6];
    unsigned u4 = edata[p + 8],  u5 = edata[p + 10], u6 = edata[p + 12], u7 = edata[p + 14];
    unsigned v0 = 0, v1 = 0, v2 = 0, v3 = 0, v4 = 0, v5 = 0, v6 = 0, v7 = 0;
    if (s < 20) {
      v0 = h2u[(size_t)(u0 & 0xffffu) * 20 + s];
      v1 = h2u[(size_t)(u1 & 0xffffu) * 20 + s];
      v2 = h2u[(size_t)(u2 & 0xffffu) * 20 + s];
      v3 = h2u[(size_t)(u3 & 0xffffu) * 20 + s];
      v4 = h2u[(size_t)(u4 & 0xffffu) * 20 + s];
      v5 = h2u[(size_t)(u5 & 0xffffu) * 20 + s];
      v6 = h2u[(size_t)(u6 & 0xffffu) * 20 + s];
      v7 = h2u[(size_t)(u7 & 0xffffu) * 20 + s];
    }
    acc0 = fmaf(hi16(u0), lo16(v0), acc0); acc1 = fmaf(hi16(u0), hi16(v0), acc1);
    acc0 = fmaf(hi16(u1), lo16(v1), acc0); acc1 = fmaf(hi16(u1), hi16(v1), acc1);
    acc0 = fmaf(hi16(u2), lo16(v2), acc0); acc1 = fmaf(hi16(u2), hi16(v2), acc1);
    acc0 = fmaf(hi16(u3), lo16(v3), acc0); acc1 = fmaf(hi16(u3), hi16(v3), acc1);
    acc0 = fmaf(hi16(u4), lo16(v4), acc0); acc1 = fmaf(hi16(u4), hi16(v4), acc1);
    acc0 = fmaf(hi16(u5), lo16(v5), acc0); acc1 = fmaf(hi16(u5), hi16(v5), acc1);
    acc0 = fmaf(hi16(u6), lo16(v6), acc0); acc1 = fmaf(hi16(u6), hi16(v6), acc1);
    acc0 = fmaf(hi16(u7), lo16(v7), acc0); acc1 = fmaf(hi16(u7), hi16(v7), acc1);
  }
  for (; p + 6 < end; p += 8) {
    unsigned u0 = edata[p], u1 = edata[p + 2], u2 = edata[p + 4], u3 = edata[p + 6];
    unsigned v0 = 0, v1 = 0, v2 = 0, v3 = 0;
    if (s < 20) {
      v0 = h2u[(size_t)(u0 & 0xffffu) * 20 + s];
      v1 = h2u[(size_t)(u1 & 0xffffu) * 20 + s];
      v2 = h2u[(size_t)(u2 & 0xffffu) * 20 + s];
      v3 = h2u[(size_t)(u3 & 0xffffu) * 20 + s];
    }
    acc0 = fmaf(hi16(u0), lo16(v0), acc0); acc1 = fmaf(hi16(u0), hi16(v0), acc1);
    acc0 = fmaf(hi16(u1), lo16(v1), acc0); acc1 = fmaf(hi16(u1), hi16(v1), acc1);
    acc0 = fmaf(hi16(u2), lo16(v2), acc0); acc1 = fmaf(hi16(u2), hi16(v2), acc1);
    acc0 = fmaf(hi16(u3), lo16(v3), acc0); acc1 = fmaf(hi16(u3), hi16(v3), acc1);
  }
  for (; p < end; p += 2) {
    unsigned u = edata[p];
    unsigned v = (s < 20) ? h2u[(size_t)(u & 0xffffu) * 20 + s] : 0u;
    acc0 = fmaf(hi16(u), lo16(v), acc0); acc1 = fmaf(hi16(u), hi16(v), acc1);
  }
  acc0 += __shfl_xor(acc0, 32);
  acc1 += __shfl_xor(acc1, 32);
  float yl = 0.f, yh = 0.f;
  if (g == 0 && s < 20) {
    float2 rv = *(const float2*)(res + (size_t)r * NCLASS + 2 * s);
    yl = fmaxf(acc0, 0.f) + rv.x;
    yh = fmaxf(acc1, 0.f) + rv.y;
  }
  float s1 = yl + yh, s2 = yl * yl + yh * yh;
#pragma unroll
  for (int off = 1; off < 32; off <<= 1) {
    s1 += __shfl_xor(s1, off);
    s2 += __shfl_xor(s2, off);
  }
  float mu = s1 / (float)NCLASS;
  float var = s2 / (float)NCLASS - mu * mu;
  float inv = rsqrtf(var + LN_EPS);
  if (g == 0 && s < 20) {
    float2 gv = *(const float2*)(ln_g + 2 * s);
    float2 bv = *(const float2*)(ln_b + 2 * s);
    float2 o;
    o.x = (yl - mu) * inv * gv.x + bv.x;
    o.y = (yh - mu) * inv * gv.y + bv.y;
    *(float2*)(out + (size_t)r * NCLASS + 2 * s) = o;
  }
}

// -------------------------------------------------------------------------------
extern "C" void kernel_launch(void* const* d_in, const int* in_sizes, int n_in,
                              void* d_out, int out_size, void* d_ws, size_t ws_size,
                              hipStream_t stream) {
  const float* x     = (const float*)d_in[0];
  const int*   ei    = (const int*)  d_in[1];
  const float* adj   = (const float*)d_in[2];
  const float* W1    = (const float*)d_in[3];
  const float* a1    = (const float*)d_in[4];
  const float* W2    = (const float*)d_in[5];
  const float* res_w = (const float*)d_in[6];
  const float* res_b = (const float*)d_in[7];
  const float* ln_g  = (const float*)d_in[8];
  const float* ln_b  = (const float*)d_in[9];
  float* out = (float*)d_out;

  char* ws = (char*)d_ws;
  size_t off = 0;
  auto alloc = [&](size_t bytes) -> void* {
    void* p = (void*)(ws + off);
    off += (bytes + 255) & ~(size_t)255;
    return p;
  };

  unsigned* h1u     = (unsigned*)alloc((size_t)N_NODES * 32 * 4);  // bf16x2 packed
  float*    s_src   = (float*)alloc((size_t)N_NODES * 4);
  float*    s_dst   = (float*)alloc((size_t)N_NODES * 4);
  int*      cnt     = (int*)  alloc((size_t)N_NODES * 4);
  int*      row_ptr = (int*)  alloc((size_t)(N_NODES + 1) * 4);
  int*      bsum    = (int*)  alloc(256 * 4);
  int*      boff    = (int*)  alloc(256 * 4);
  unsigned* edata   = (unsigned*)alloc((size_t)N_EDGES * 4);       // col:16|w:bf16
  unsigned* h2u     = (unsigned*)alloc((size_t)N_NODES * 20 * 4);  // bf16x2 packed
  float*    res     = (float*)alloc((size_t)N_NODES * NCLASS * 4);
  (void)ws_size; (void)in_sizes; (void)n_in; (void)out_size;

  const int NBLK_NODE = N_NODES / 4;            // 12500
  const int NBLK_EDGE = (N_EDGES + 255) / 256;  // 3125
  const int NBLK_SCAN = (N_NODES + 255) / 256;  // 196
  const int NBLK_H1   = (N_NODES + 63) / 64;    // 782
  const int NBLK_RES  = (N_NODES + 127) / 128;  // 391

  hipMemsetAsync(cnt, 0, (size_t)N_NODES * 4, stream);
  k_h1mm<<<NBLK_H1, 256, 0, stream>>>(x, W1, a1, h1u, s_src, s_dst);
  k_resmm<<<NBLK_RES, 256, 0, stream>>>(x, res_w, res_b, res);
  k_hist<<<NBLK_EDGE, 256, 0, stream>>>(ei, cnt);
  k_scan1<<<NBLK_SCAN, 256, 0, stream>>>(cnt, row_ptr, bsum);
  k_scan2<<<1, 256, 0, stream>>>(bsum, boff, NBLK_SCAN, row_ptr + N_NODES);
  k_scan3<<<NBLK_SCAN, 256, 0, stream>>>(row_ptr, boff);
  hipMemsetAsync(cnt, 0, (size_t)N_NODES * 4, stream);
  k_scatter<<<NBLK_EDGE, 256, 0, stream>>>(ei, adj, s_src, s_dst, row_ptr, cnt, edata);
  k_agg1<<<NBLK_NODE, 256, 0, stream>>>(h1u, edata, row_ptr, W2, h2u);
  k_agg2<<<NBLK_NODE, 256, 0, stream>>>(h2u, edata, row_ptr, res, ln_g, ln_b, out);
}